// Round 11
// baseline (592.240 us; speedup 1.0000x reference)
//
#include <hip/hip_runtime.h>

using f32x4 = float    __attribute__((ext_vector_type(4)));
using f16x8 = _Float16 __attribute__((ext_vector_type(8)));
using f16x4 = _Float16 __attribute__((ext_vector_type(4)));

__device__ __forceinline__ void gload_lds16(const void* g, void* l) {
    __builtin_amdgcn_global_load_lds(
        (__attribute__((address_space(1))) void*)(void*)g,
        (__attribute__((address_space(3))) void*)l, 16, 0, 0);
}

// BK=64 swizzle (validated R8): rows 128B apart, 8 slots of 16B, rotate by row:
//   stage: lane seg=lane&7 row r8=lane>>3 pulls k-seg ((seg-r8)&7)
//   read:  k-seg (quad+4*ks) of row lrow at slot ((quad+4*ks+lrow)&7)
// GEMM2 tile ledger (K=512): 256x128 @512thr = 12 B staged/elem (R8, BEST);
//   128x128 (R9, +15), 64x256-ares (R4, worse). Noise floor ±20-30us — only
//   structural (>30us) changes are resolvable.

// ------- merged prep: cvt X->fp16 AND outf=X; transpose-convert W -----------
// blocks [0,2048): 2048 X-elems each (Xh f16 + outf f32 residual base)
// blocks [2048,2560): 32x32 W transpose tiles
__global__ __launch_bounds__(256) void k_prep(
    const float* __restrict__ X, _Float16* __restrict__ Xh,
    float* __restrict__ outf,
    const float* __restrict__ W, _Float16* __restrict__ Wt) {
    int b = blockIdx.x;
    if (b < 2048) {
        int i = (b * 256 + threadIdx.x) * 8;
        f32x4 a = *(const f32x4*)(X + i);
        f32x4 c = *(const f32x4*)(X + i + 4);
        f16x8 o;
        #pragma unroll
        for (int j = 0; j < 4; ++j) { o[j] = (_Float16)a[j]; o[j + 4] = (_Float16)c[j]; }
        *(f16x8*)(Xh + i) = o;
        *(f32x4*)(outf + i) = a;          // residual base for GEMM3 atomics
        *(f32x4*)(outf + i + 4) = c;
    } else {
        __shared__ _Float16 tile[32][33];
        int tb = b - 2048;                   // 512 tiles: W [512,1024]
        int c0 = (tb & 31) * 32, r0 = (tb >> 5) * 32;
        int tx = threadIdx.x & 31, ty = threadIdx.x >> 5;
        #pragma unroll
        for (int i = ty; i < 32; i += 8)
            tile[i][tx] = (_Float16)W[(size_t)(r0 + i) * 1024 + c0 + tx];
        __syncthreads();
        #pragma unroll
        for (int i = ty; i < 32; i += 8)
            Wt[(size_t)(c0 + i) * 512 + r0 + tx] = tile[tx][i];
    }
}

// ------- fused GEMM1: Wh/Ws pair + tanh + transposed Wh output (R7-valid) ---
__global__ __launch_bounds__(512, 4) void k_gemm1f(
    const _Float16* __restrict__ A, const _Float16* __restrict__ Bt,
    _Float16* __restrict__ Whh, _Float16* __restrict__ T,
    _Float16* __restrict__ WhT,
    const float* __restrict__ aw, const float* __restrict__ ab) {
    __shared__ _Float16 As[128 * 32];
    __shared__ _Float16 B0s[64 * 32];
    __shared__ _Float16 B1s[64 * 32];
    const float bias = aw[0] + ab[0];
    const int row0 = blockIdx.y * 128, col0 = blockIdx.x * 64;
    const int tid = threadIdx.x, w = tid >> 6, lane = tid & 63;
    const int wm = w >> 2, wn = w & 3;
    const int lrow = lane & 15, quad = lane >> 4;
    const int r16 = lane >> 2;
    const int kc = (((lane & 3) - ((lane >> 3) & 3)) & 3) * 8;
    const int sq = ((quad + ((lrow >> 1) & 3)) & 3) * 8;
    f32x4 acc0[4] = {}, acc1[4] = {};
    for (int k0 = 0; k0 < 512; k0 += 32) {
        gload_lds16(A + (size_t)(row0 + w * 16 + r16) * 512 + k0 + kc,
                    As + w * 512);
        if (w < 4)
            gload_lds16(Bt + (size_t)(col0 + w * 16 + r16) * 512 + k0 + kc,
                        B0s + w * 512);
        else
            gload_lds16(Bt + (size_t)(col0 + 512 + (w - 4) * 16 + r16) * 512 + k0 + kc,
                        B1s + (w - 4) * 512);
        __syncthreads();
        f16x8 af[4], b0, b1;
        #pragma unroll
        for (int i = 0; i < 4; ++i)
            af[i] = *(const f16x8*)(As + (wm * 64 + i * 16 + lrow) * 32 + sq);
        b0 = *(const f16x8*)(B0s + (wn * 16 + lrow) * 32 + sq);
        b1 = *(const f16x8*)(B1s + (wn * 16 + lrow) * 32 + sq);
        #pragma unroll
        for (int mi = 0; mi < 4; ++mi) {
            acc0[mi] = __builtin_amdgcn_mfma_f32_16x16x32_f16(af[mi], b0, acc0[mi], 0, 0, 0);
            acc1[mi] = __builtin_amdgcn_mfma_f32_16x16x32_f16(af[mi], b1, acc1[mi], 0, 0, 0);
        }
        __syncthreads();
    }
    const int col = col0 + wn * 16 + lrow;
    #pragma unroll
    for (int mi = 0; mi < 4; ++mi) {
        int rowb = row0 + wm * 64 + mi * 16 + quad * 4;
        f16x4 pw;
        #pragma unroll
        for (int r = 0; r < 4; ++r) {
            float wh = acc0[mi][r];
            float tt = tanhf(wh + acc1[mi][r] + bias);
            Whh[(size_t)(rowb + r) * 512 + col] = (_Float16)wh;
            T[(size_t)(rowb + r) * 512 + col]   = (_Float16)tt;
            pw[r] = (_Float16)wh;
        }
        *(f16x4*)(WhT + (size_t)col * 8192 + rowb) = pw;
    }
}

// ---------------- GEMM2: S = T @ Whh^T  (BM=256, BN=128, BK=64, R8-exact) ---
__global__ __launch_bounds__(512, 4) void k_gemm2(
    const _Float16* __restrict__ A,      // T [8192,512]
    const _Float16* __restrict__ Bt,     // Whh [8192,512]
    _Float16* __restrict__ Cp) {         // S [8192,8192]
    __shared__ _Float16 As[256 * 64];
    __shared__ _Float16 Bs[128 * 64];
    const int row0 = blockIdx.y * 256, col0 = blockIdx.x * 128;
    const int tid = threadIdx.x, w = tid >> 6, lane = tid & 63;
    const int wm = w >> 1, wn = w & 1;
    const int lrow = lane & 15, quad = lane >> 4;
    const int r8 = lane >> 3;
    const int kc8 = (((lane & 7) - r8) & 7) * 8;
    f32x4 acc[4][4] = {};
    for (int k0 = 0; k0 < 512; k0 += 64) {
        #pragma unroll
        for (int i = 0; i < 6; ++i) {
            int c = w + i * 8;                      // 48 chunks
            if (c < 32) {
                gload_lds16(A + (size_t)(row0 + c * 8 + r8) * 512 + k0 + kc8,
                            As + c * 512);
            } else {
                int c2 = c - 32;
                gload_lds16(Bt + (size_t)(col0 + c2 * 8 + r8) * 512 + k0 + kc8,
                            Bs + c2 * 512);
            }
        }
        __syncthreads();
        #pragma unroll
        for (int ks = 0; ks < 2; ++ks) {
            const int sl = ((quad + ks * 4 + lrow) & 7) * 8;
            f16x8 af[4], bf[4];
            #pragma unroll
            for (int i = 0; i < 4; ++i)
                af[i] = *(const f16x8*)(As + (wm * 64 + i * 16 + lrow) * 64 + sl);
            #pragma unroll
            for (int i = 0; i < 4; ++i)
                bf[i] = *(const f16x8*)(Bs + (wn * 64 + i * 16 + lrow) * 64 + sl);
            #pragma unroll
            for (int mi = 0; mi < 4; ++mi)
                #pragma unroll
                for (int ni = 0; ni < 4; ++ni)
                    acc[mi][ni] = __builtin_amdgcn_mfma_f32_16x16x32_f16(
                        af[mi], bf[ni], acc[mi][ni], 0, 0, 0);
        }
        __syncthreads();
    }
    #pragma unroll
    for (int mi = 0; mi < 4; ++mi) {
        #pragma unroll
        for (int ni = 0; ni < 4; ++ni) {
            int col = col0 + wn * 64 + ni * 16 + lrow;
            #pragma unroll
            for (int r = 0; r < 4; ++r) {
                int row = row0 + wm * 64 + mi * 16 + quad * 4 + r;
                Cp[(size_t)row * 8192 + col] = (_Float16)acc[mi][ni][r];
            }
        }
    }
}

// ------- GEMM3: outf += P[:, zchunk] @ Wh[zchunk, :]  (atomic epilogue) -----
// K-loop R8-exact (BM=128 BN=256 BK=64, 512 thr, z=4). Epilogue does HW f32
// atomic adds into outf (pre-initialized to X by k_prep) — removes the part
// buffers (64MB W + 64MB R) and the 96MB reduce pass entirely.
__global__ __launch_bounds__(512, 4) void k_gemm3(
    const _Float16* __restrict__ A,      // P [8192][8192]
    const _Float16* __restrict__ Bt,     // WhT [512][8192]
    float* __restrict__ outf) {          // [8192,512] fp32, base = X
    __shared__ _Float16 As[128 * 64];
    __shared__ _Float16 Bs[256 * 64];
    const int row0 = blockIdx.y * 128, col0 = blockIdx.x * 256;
    const size_t zoff = (size_t)blockIdx.z * 2048;
    const int tid = threadIdx.x, w = tid >> 6, lane = tid & 63;
    const int wm = w >> 2, wn = w & 3;
    const int lrow = lane & 15, quad = lane >> 4;
    const int r8 = lane >> 3;
    const int kc8 = (((lane & 7) - r8) & 7) * 8;
    f32x4 acc[4][4] = {};
    for (int k0 = 0; k0 < 2048; k0 += 64) {
        #pragma unroll
        for (int i = 0; i < 6; ++i) {
            int c = w + i * 8;                      // 48 chunks (16 A + 32 B)
            if (c < 16) {
                gload_lds16(A + (size_t)(row0 + c * 8 + r8) * 8192 + zoff + k0 + kc8,
                            As + c * 512);
            } else {
                int c2 = c - 16;
                gload_lds16(Bt + (size_t)(col0 + c2 * 8 + r8) * 8192 + zoff + k0 + kc8,
                            Bs + c2 * 512);
            }
        }
        __syncthreads();
        #pragma unroll
        for (int ks = 0; ks < 2; ++ks) {
            const int sl = ((quad + ks * 4 + lrow) & 7) * 8;
            f16x8 af[4], bf[4];
            #pragma unroll
            for (int i = 0; i < 4; ++i)
                af[i] = *(const f16x8*)(As + (wm * 64 + i * 16 + lrow) * 64 + sl);
            #pragma unroll
            for (int i = 0; i < 4; ++i)
                bf[i] = *(const f16x8*)(Bs + (wn * 64 + i * 16 + lrow) * 64 + sl);
            #pragma unroll
            for (int mi = 0; mi < 4; ++mi)
                #pragma unroll
                for (int ni = 0; ni < 4; ++ni)
                    acc[mi][ni] = __builtin_amdgcn_mfma_f32_16x16x32_f16(
                        af[mi], bf[ni], acc[mi][ni], 0, 0, 0);
        }
        __syncthreads();
    }
    #pragma unroll
    for (int mi = 0; mi < 4; ++mi) {
        #pragma unroll
        for (int ni = 0; ni < 4; ++ni) {
            int col = col0 + wn * 64 + ni * 16 + lrow;
            #pragma unroll
            for (int r = 0; r < 4; ++r) {
                int row = row0 + wm * 64 + mi * 16 + quad * 4 + r;
                unsafeAtomicAdd(&outf[(size_t)row * 512 + col], acc[mi][ni][r]);
            }
        }
    }
}

// ---------------- row softmax in place: S fp16 -> P fp16 --------------------
__global__ __launch_bounds__(256) void k_softmax_rows(
    _Float16* __restrict__ S, int N) {
    const int row = blockIdx.x;
    _Float16* prow = S + (size_t)row * N;
    const int t = threadIdx.x;
    float v[32];
    #pragma unroll
    for (int it = 0; it < 4; ++it) {
        f16x8 h = *(const f16x8*)(prow + (it * 256 + t) * 8);
        #pragma unroll
        for (int j = 0; j < 8; ++j) v[it * 8 + j] = (float)h[j];
    }
    float m = v[0];
    #pragma unroll
    for (int j = 1; j < 32; ++j) m = fmaxf(m, v[j]);
    #pragma unroll
    for (int off = 32; off > 0; off >>= 1) m = fmaxf(m, __shfl_xor(m, off));
    __shared__ float red[8];
    const int wid = t >> 6, lane = t & 63;
    if (lane == 0) red[wid] = m;
    __syncthreads();
    m = fmaxf(fmaxf(red[0], red[1]), fmaxf(red[2], red[3]));
    float l = 0.f;
    #pragma unroll
    for (int j = 0; j < 32; ++j) { v[j] = __expf(v[j] - m); l += v[j]; }
    #pragma unroll
    for (int off = 32; off > 0; off >>= 1) l += __shfl_xor(l, off);
    if (lane == 0) red[4 + wid] = l;
    __syncthreads();
    float rl = 1.f / (red[4] + red[5] + red[6] + red[7]);
    #pragma unroll
    for (int it = 0; it < 4; ++it) {
        f16x8 pk;
        #pragma unroll
        for (int j = 0; j < 8; ++j)
            pk[j] = (_Float16)(v[it * 8 + j] * rl);
        *(f16x8*)(prow + (it * 256 + t) * 8) = pk;
    }
}

// ---------------- column sum/sumsq over completed outf ----------------------
// 256 blocks x 32 rows, f32x4 lanes: thread t -> cols (t&127)*4, rows half.
__global__ __launch_bounds__(256) void k_colstats(
    const float* __restrict__ outf, float* __restrict__ cs,
    float* __restrict__ cq) {
    const int t = threadIdx.x;
    const int r0 = blockIdx.x * 32;
    const int colg = (t & 127) * 4;
    const int rofs = (t >> 7) * 16;
    float s[4] = {}, q[4] = {};
    for (int it = 0; it < 16; ++it) {
        size_t base = (size_t)(r0 + rofs + it) * 512 + colg;
        f32x4 o = *(const f32x4*)(outf + base);
        #pragma unroll
        for (int j = 0; j < 4; ++j) { s[j] += o[j]; q[j] += o[j] * o[j]; }
    }
    #pragma unroll
    for (int j = 0; j < 4; ++j) {
        unsafeAtomicAdd(&cs[colg + j], s[j]);
        unsafeAtomicAdd(&cq[colg + j], q[j]);
    }
}

// ---------------- batchnorm (no affine) + leaky relu -> fp32, f32x4 ---------
__global__ __launch_bounds__(256) void k_bn_lrelu(
    const float* __restrict__ outf, const float* __restrict__ colsum,
    const float* __restrict__ colsq, float* __restrict__ out) {
    int i = (blockIdx.x * 256 + threadIdx.x) * 4;
    int c = i & 511;
    constexpr float rN = 1.f / 8192.f;
    f32x4 o = *(const f32x4*)(outf + i);
    f32x4 r;
    #pragma unroll
    for (int j = 0; j < 4; ++j) {
        float mean = colsum[c + j] * rN;
        float var  = colsq[c + j] * rN - mean * mean;
        float y = (o[j] - mean) * rsqrtf(var + 1e-5f);
        r[j] = (y >= 0.f) ? y : 0.01f * y;
    }
    *(f32x4*)(out + i) = r;
}

extern "C" void kernel_launch(void* const* d_in, const int* in_sizes, int n_in,
                              void* d_out, int out_size, void* d_ws, size_t ws_size,
                              hipStream_t stream) {
    const float* X  = (const float*)d_in[0];  // [8192,512] fp32
    // d_in[1] = adj, unused
    const float* W  = (const float*)d_in[2];  // [512,1024] fp32
    const float* aw = (const float*)d_in[3];
    const float* ab = (const float*)d_in[4];
    float* out = (float*)d_out;               // [8192,512] fp32

    char* ws = (char*)d_ws;
    _Float16* Xh   = (_Float16*)(ws + 0x0);          //   8 MB [8192,512]
    _Float16* Wt   = (_Float16*)(ws + 0x800000);     //   1 MB W^T [1024,512]
    _Float16* T    = (_Float16*)(ws + 0x900000);     //   8 MB [8192,512]
    _Float16* Whh  = (_Float16*)(ws + 0x1100000);    //   8 MB [8192,512]
    _Float16* WhT  = (_Float16*)(ws + 0x1900000);    //   8 MB [512,8192]
    _Float16* S    = (_Float16*)(ws + 0x2100000);    // 128 MB [8192,8192] fp16
    float*    outf = (float*)   (ws + 0xA100000);    //  16 MB [8192,512] fp32
    float*    cs   = (float*)   (ws + 0xB100000);    //   2 KB
    float*    cq   = (float*)   (ws + 0xB100800);    //   2 KB

    // stats accumulators zeroed up-front
    hipMemsetAsync(cs, 0, 4096, stream);
    // 0. merged prep: Xh = fp16(X); outf = X; Wt = fp16(W^T)
    k_prep<<<dim3(2560), 256, 0, stream>>>(X, Xh, outf, W, Wt);
    // 1. fused: Whh/T/WhT from Xh @ Wt (both halves + tanh + transpose)
    k_gemm1f<<<dim3(8, 64), 512, 0, stream>>>(Xh, Wt, Whh, T, WhT, aw, ab);
    // 2. S = T @ Whh^T  (fp16)  M=8192 N=8192 K=512, 256x128 tile BK=64
    k_gemm2<<<dim3(64, 32), 512, 0, stream>>>(T, Whh, S);
    // 3. row softmax in place: S -> P (fp16)
    k_softmax_rows<<<dim3(8192), 256, 0, stream>>>(S, 8192);
    // 4. outf += P @ Wh  (atomic epilogue; outf pre-seeded with X)
    k_gemm3<<<dim3(2, 64, 4), 512, 0, stream>>>(S, WhT, outf);
    // 5. column stats over completed outf
    k_colstats<<<dim3(256), 256, 0, stream>>>(outf, cs, cq);
    // 6. batchnorm + leaky relu (f32x4)
    k_bn_lrelu<<<dim3((8192 * 512) / 1024), 256, 0, stream>>>(outf, cs, cq, out);
}

// Round 12
// 516.998 us; speedup vs baseline: 1.1455x; 1.1455x over previous
//
#include <hip/hip_runtime.h>

using f32x4 = float    __attribute__((ext_vector_type(4)));
using f16x8 = _Float16 __attribute__((ext_vector_type(8)));
using f16x4 = _Float16 __attribute__((ext_vector_type(4)));

__device__ __forceinline__ void gload_lds16(const void* g, void* l) {
    __builtin_amdgcn_global_load_lds(
        (__attribute__((address_space(1))) void*)(void*)g,
        (__attribute__((address_space(3))) void*)l, 16, 0, 0);
}

// BK=32 swizzle (validated R3/R6/R7), rows 64B apart, 4 slots of 16B:
//   stage: lane seg=lane&3 row r16=lane>>2 pulls k-seg ((seg-(r16>>1))&3)
//   read:  k-seg `quad` of row lrow at slot ((quad+(lrow>>1))&3)
// BK=64 swizzle (validated R8): rows 128B apart, 8 slots of 16B, rotate by row:
//   stage: lane seg=lane&7 row r8=lane>>3 pulls k-seg ((seg-r8)&7)
//   read:  k-seg (quad+4*ks) of row lrow at slot ((quad+4*ks+lrow)&7)
// Ledger: R8=509.7 BEST. R9 (GEMM2 128^2) +15. R10 (vec epilogues+merged prep)
// +37.6. R11 (atomic GEMM3 epilogue) +82.5 — atomics serialize on L2, rejected.
// This round: R8 verbatim re-bench (A/A test to size inter-round noise).

// ---------------- fp32 -> fp16 elementwise convert (8 elems/thread) ---------
__global__ __launch_bounds__(256) void k_cvt_x(
    const float* __restrict__ in, _Float16* __restrict__ out) {
    int i = (blockIdx.x * 256 + threadIdx.x) * 8;
    f32x4 a = *(const f32x4*)(in + i);
    f32x4 b = *(const f32x4*)(in + i + 4);
    f16x8 o;
    #pragma unroll
    for (int j = 0; j < 4; ++j) { o[j] = (_Float16)a[j]; o[j + 4] = (_Float16)b[j]; }
    *(f16x8*)(out + i) = o;
}

// ---------------- fp32 in [R][C] -> fp16 out[c][r] (convert + transpose) ----
__global__ __launch_bounds__(256) void k_cvtT(
    const float* __restrict__ in, _Float16* __restrict__ out, int R, int C) {
    __shared__ _Float16 tile[32][33];
    int c0 = blockIdx.x * 32, r0 = blockIdx.y * 32;
    int tx = threadIdx.x & 31, ty = threadIdx.x >> 5;
    #pragma unroll
    for (int i = ty; i < 32; i += 8)
        tile[i][tx] = (_Float16)in[(size_t)(r0 + i) * C + c0 + tx];
    __syncthreads();
    #pragma unroll
    for (int i = ty; i < 32; i += 8)
        out[(size_t)(c0 + i) * R + r0 + tx] = tile[tx][i];
}

// ------- fused GEMM1: Wh/Ws pair + tanh + transposed Wh output (R7-valid) ---
__global__ __launch_bounds__(512, 4) void k_gemm1f(
    const _Float16* __restrict__ A, const _Float16* __restrict__ Bt,
    _Float16* __restrict__ Whh, _Float16* __restrict__ T,
    _Float16* __restrict__ WhT,
    const float* __restrict__ aw, const float* __restrict__ ab) {
    __shared__ _Float16 As[128 * 32];
    __shared__ _Float16 B0s[64 * 32];
    __shared__ _Float16 B1s[64 * 32];
    const float bias = aw[0] + ab[0];
    const int row0 = blockIdx.y * 128, col0 = blockIdx.x * 64;
    const int tid = threadIdx.x, w = tid >> 6, lane = tid & 63;
    const int wm = w >> 2, wn = w & 3;
    const int lrow = lane & 15, quad = lane >> 4;
    const int r16 = lane >> 2;
    const int kc = (((lane & 3) - ((lane >> 3) & 3)) & 3) * 8;
    const int sq = ((quad + ((lrow >> 1) & 3)) & 3) * 8;
    f32x4 acc0[4] = {}, acc1[4] = {};
    for (int k0 = 0; k0 < 512; k0 += 32) {
        gload_lds16(A + (size_t)(row0 + w * 16 + r16) * 512 + k0 + kc,
                    As + w * 512);
        if (w < 4)
            gload_lds16(Bt + (size_t)(col0 + w * 16 + r16) * 512 + k0 + kc,
                        B0s + w * 512);
        else
            gload_lds16(Bt + (size_t)(col0 + 512 + (w - 4) * 16 + r16) * 512 + k0 + kc,
                        B1s + (w - 4) * 512);
        __syncthreads();
        f16x8 af[4], b0, b1;
        #pragma unroll
        for (int i = 0; i < 4; ++i)
            af[i] = *(const f16x8*)(As + (wm * 64 + i * 16 + lrow) * 32 + sq);
        b0 = *(const f16x8*)(B0s + (wn * 16 + lrow) * 32 + sq);
        b1 = *(const f16x8*)(B1s + (wn * 16 + lrow) * 32 + sq);
        #pragma unroll
        for (int mi = 0; mi < 4; ++mi) {
            acc0[mi] = __builtin_amdgcn_mfma_f32_16x16x32_f16(af[mi], b0, acc0[mi], 0, 0, 0);
            acc1[mi] = __builtin_amdgcn_mfma_f32_16x16x32_f16(af[mi], b1, acc1[mi], 0, 0, 0);
        }
        __syncthreads();
    }
    const int col = col0 + wn * 16 + lrow;
    #pragma unroll
    for (int mi = 0; mi < 4; ++mi) {
        int rowb = row0 + wm * 64 + mi * 16 + quad * 4;
        f16x4 pw;
        #pragma unroll
        for (int r = 0; r < 4; ++r) {
            float wh = acc0[mi][r];
            float tt = tanhf(wh + acc1[mi][r] + bias);
            Whh[(size_t)(rowb + r) * 512 + col] = (_Float16)wh;
            T[(size_t)(rowb + r) * 512 + col]   = (_Float16)tt;
            pw[r] = (_Float16)wh;
        }
        *(f16x4*)(WhT + (size_t)col * 8192 + rowb) = pw;
    }
}

// ---------------- GEMM2: S = T @ Whh^T  (BM=256, BN=128, BK=64) -------------
// R8-validated best (12 B staged/elem). 512 thr / 8 waves (4x2); 48 chunks /
// 8 waves = 6 gloads per 64-k iter; one barrier per 64-k. grid (64,32).
__global__ __launch_bounds__(512, 4) void k_gemm2(
    const _Float16* __restrict__ A,      // T [8192,512]
    const _Float16* __restrict__ Bt,     // Whh [8192,512]
    _Float16* __restrict__ Cp) {         // S [8192,8192]
    __shared__ _Float16 As[256 * 64];
    __shared__ _Float16 Bs[128 * 64];
    const int row0 = blockIdx.y * 256, col0 = blockIdx.x * 128;
    const int tid = threadIdx.x, w = tid >> 6, lane = tid & 63;
    const int wm = w >> 1, wn = w & 1;
    const int lrow = lane & 15, quad = lane >> 4;
    const int r8 = lane >> 3;                       // row within 8-row chunk
    const int kc8 = (((lane & 7) - r8) & 7) * 8;    // staged source k-seg
    f32x4 acc[4][4] = {};
    for (int k0 = 0; k0 < 512; k0 += 64) {
        #pragma unroll
        for (int i = 0; i < 6; ++i) {
            int c = w + i * 8;                      // 48 chunks
            if (c < 32) {
                gload_lds16(A + (size_t)(row0 + c * 8 + r8) * 512 + k0 + kc8,
                            As + c * 512);
            } else {
                int c2 = c - 32;
                gload_lds16(Bt + (size_t)(col0 + c2 * 8 + r8) * 512 + k0 + kc8,
                            Bs + c2 * 512);
            }
        }
        __syncthreads();
        #pragma unroll
        for (int ks = 0; ks < 2; ++ks) {
            const int sl = ((quad + ks * 4 + lrow) & 7) * 8;
            f16x8 af[4], bf[4];
            #pragma unroll
            for (int i = 0; i < 4; ++i)
                af[i] = *(const f16x8*)(As + (wm * 64 + i * 16 + lrow) * 64 + sl);
            #pragma unroll
            for (int i = 0; i < 4; ++i)
                bf[i] = *(const f16x8*)(Bs + (wn * 64 + i * 16 + lrow) * 64 + sl);
            #pragma unroll
            for (int mi = 0; mi < 4; ++mi)
                #pragma unroll
                for (int ni = 0; ni < 4; ++ni)
                    acc[mi][ni] = __builtin_amdgcn_mfma_f32_16x16x32_f16(
                        af[mi], bf[ni], acc[mi][ni], 0, 0, 0);
        }
        __syncthreads();
    }
    #pragma unroll
    for (int mi = 0; mi < 4; ++mi) {
        #pragma unroll
        for (int ni = 0; ni < 4; ++ni) {
            int col = col0 + wn * 64 + ni * 16 + lrow;
            #pragma unroll
            for (int r = 0; r < 4; ++r) {
                int row = row0 + wm * 64 + mi * 16 + quad * 4 + r;
                Cp[(size_t)row * 8192 + col] = (_Float16)acc[mi][ni][r];
            }
        }
    }
}

// ------- GEMM3: part[z] = P[:, zchunk] @ Wh[zchunk, :]  (BK=64, R8-valid) ---
__global__ __launch_bounds__(512, 4) void k_gemm3(
    const _Float16* __restrict__ A,      // P [8192][8192]
    const _Float16* __restrict__ Bt,     // WhT [512][8192]
    float* __restrict__ Cp) {            // partials [4][8192][512]
    __shared__ _Float16 As[128 * 64];
    __shared__ _Float16 Bs[256 * 64];
    const int row0 = blockIdx.y * 128, col0 = blockIdx.x * 256;
    const size_t zoff = (size_t)blockIdx.z * 2048;
    Cp += (size_t)blockIdx.z * ((size_t)8192 * 512);
    const int tid = threadIdx.x, w = tid >> 6, lane = tid & 63;
    const int wm = w >> 2, wn = w & 3;
    const int lrow = lane & 15, quad = lane >> 4;
    const int r8 = lane >> 3;
    const int kc8 = (((lane & 7) - r8) & 7) * 8;
    f32x4 acc[4][4] = {};
    for (int k0 = 0; k0 < 2048; k0 += 64) {
        #pragma unroll
        for (int i = 0; i < 6; ++i) {
            int c = w + i * 8;                      // 48 chunks (16 A + 32 B)
            if (c < 16) {
                gload_lds16(A + (size_t)(row0 + c * 8 + r8) * 8192 + zoff + k0 + kc8,
                            As + c * 512);
            } else {
                int c2 = c - 16;
                gload_lds16(Bt + (size_t)(col0 + c2 * 8 + r8) * 8192 + zoff + k0 + kc8,
                            Bs + c2 * 512);
            }
        }
        __syncthreads();
        #pragma unroll
        for (int ks = 0; ks < 2; ++ks) {
            const int sl = ((quad + ks * 4 + lrow) & 7) * 8;
            f16x8 af[4], bf[4];
            #pragma unroll
            for (int i = 0; i < 4; ++i)
                af[i] = *(const f16x8*)(As + (wm * 64 + i * 16 + lrow) * 64 + sl);
            #pragma unroll
            for (int i = 0; i < 4; ++i)
                bf[i] = *(const f16x8*)(Bs + (wn * 64 + i * 16 + lrow) * 64 + sl);
            #pragma unroll
            for (int mi = 0; mi < 4; ++mi)
                #pragma unroll
                for (int ni = 0; ni < 4; ++ni)
                    acc[mi][ni] = __builtin_amdgcn_mfma_f32_16x16x32_f16(
                        af[mi], bf[ni], acc[mi][ni], 0, 0, 0);
        }
        __syncthreads();
    }
    #pragma unroll
    for (int mi = 0; mi < 4; ++mi) {
        #pragma unroll
        for (int ni = 0; ni < 4; ++ni) {
            int col = col0 + wn * 64 + ni * 16 + lrow;
            #pragma unroll
            for (int r = 0; r < 4; ++r) {
                int row = row0 + wm * 64 + mi * 16 + quad * 4 + r;
                Cp[(size_t)row * 512 + col] = acc[mi][ni][r];
            }
        }
    }
}

// ---------------- row softmax in place: S fp16 -> P fp16 --------------------
__global__ __launch_bounds__(256) void k_softmax_rows(
    _Float16* __restrict__ S, int N) {
    const int row = blockIdx.x;
    _Float16* prow = S + (size_t)row * N;
    const int t = threadIdx.x;
    float v[32];
    #pragma unroll
    for (int it = 0; it < 4; ++it) {
        f16x8 h = *(const f16x8*)(prow + (it * 256 + t) * 8);
        #pragma unroll
        for (int j = 0; j < 8; ++j) v[it * 8 + j] = (float)h[j];
    }
    float m = v[0];
    #pragma unroll
    for (int j = 1; j < 32; ++j) m = fmaxf(m, v[j]);
    #pragma unroll
    for (int off = 32; off > 0; off >>= 1) m = fmaxf(m, __shfl_xor(m, off));
    __shared__ float red[8];
    const int wid = t >> 6, lane = t & 63;
    if (lane == 0) red[wid] = m;
    __syncthreads();
    m = fmaxf(fmaxf(red[0], red[1]), fmaxf(red[2], red[3]));
    float l = 0.f;
    #pragma unroll
    for (int j = 0; j < 32; ++j) { v[j] = __expf(v[j] - m); l += v[j]; }
    #pragma unroll
    for (int off = 32; off > 0; off >>= 1) l += __shfl_xor(l, off);
    if (lane == 0) red[4 + wid] = l;
    __syncthreads();
    float rl = 1.f / (red[4] + red[5] + red[6] + red[7]);
    #pragma unroll
    for (int it = 0; it < 4; ++it) {
        f16x8 pk;
        #pragma unroll
        for (int j = 0; j < 8; ++j)
            pk[j] = (_Float16)(v[it * 8 + j] * rl);
        *(f16x8*)(prow + (it * 256 + t) * 8) = pk;
    }
}

// ------- fused: outf = sum(part[0..3]) + X, plus column sum/sumsq atomics ---
__global__ __launch_bounds__(256) void k_reduce_stats(
    const float* __restrict__ part, const float* __restrict__ X,
    float* __restrict__ outf, float* __restrict__ cs, float* __restrict__ cq) {
    const int t = threadIdx.x;
    const int r0 = blockIdx.x * 32;
    constexpr size_t PS = (size_t)8192 * 512;
    float s0 = 0, q0 = 0, s1 = 0, q1 = 0;
    for (int r = 0; r < 32; ++r) {
        size_t base = (size_t)(r0 + r) * 512;
        float a = part[base + t] + part[PS + base + t]
                + part[2 * PS + base + t] + part[3 * PS + base + t] + X[base + t];
        float b = part[base + t + 256] + part[PS + base + t + 256]
                + part[2 * PS + base + t + 256] + part[3 * PS + base + t + 256]
                + X[base + t + 256];
        outf[base + t] = a;       outf[base + t + 256] = b;
        s0 += a; q0 += a * a; s1 += b; q1 += b * b;
    }
    atomicAdd(&cs[t], s0);       atomicAdd(&cq[t], q0);
    atomicAdd(&cs[t + 256], s1); atomicAdd(&cq[t + 256], q1);
}

// ---------------- batchnorm (no affine) + leaky relu -> fp32 ----------------
__global__ __launch_bounds__(256) void k_bn_lrelu(
    const float* __restrict__ outf, const float* __restrict__ colsum,
    const float* __restrict__ colsq, float* __restrict__ out) {
    int i = blockIdx.x * 256 + threadIdx.x;
    int c = i & 511;
    constexpr float rN = 1.f / 8192.f;
    float mean = colsum[c] * rN;
    float var  = colsq[c] * rN - mean * mean;
    float y = (outf[i] - mean) * rsqrtf(var + 1e-5f);
    y = (y >= 0.f) ? y : 0.01f * y;
    out[i] = y;
}

extern "C" void kernel_launch(void* const* d_in, const int* in_sizes, int n_in,
                              void* d_out, int out_size, void* d_ws, size_t ws_size,
                              hipStream_t stream) {
    const float* X  = (const float*)d_in[0];  // [8192,512] fp32
    // d_in[1] = adj, unused
    const float* W  = (const float*)d_in[2];  // [512,1024] fp32
    const float* aw = (const float*)d_in[3];
    const float* ab = (const float*)d_in[4];
    float* out = (float*)d_out;               // [8192,512] fp32

    char* ws = (char*)d_ws;
    _Float16* Xh   = (_Float16*)(ws + 0x0);          //   8 MB [8192,512]
    _Float16* Wt   = (_Float16*)(ws + 0x800000);     //   1 MB W^T [1024,512]
    _Float16* T    = (_Float16*)(ws + 0x900000);     //   8 MB [8192,512]
    _Float16* Whh  = (_Float16*)(ws + 0x1100000);    //   8 MB [8192,512]
    _Float16* WhT  = (_Float16*)(ws + 0x1900000);    //   8 MB [512,8192]
    _Float16* S    = (_Float16*)(ws + 0x2100000);    // 128 MB [8192,8192] fp16
    float*    outf = (float*)   (ws + 0xA100000);    //  16 MB [8192,512] fp32
    float*    part = (float*)   (ws + 0xB100000);    //  64 MB 4x[8192,512] fp32
    float*    cs   = (float*)   (ws + 0xF100000);    //   2 KB
    float*    cq   = (float*)   (ws + 0xF100800);    //   2 KB

    // stats accumulators zeroed up-front
    hipMemsetAsync(cs, 0, 4096, stream);
    // 0. Xh = fp16(X);  Wt = fp16(W^T)
    k_cvt_x<<<dim3((8192 * 512) / 2048), 256, 0, stream>>>(X, Xh);
    k_cvtT<<<dim3(1024 / 32, 512 / 32), 256, 0, stream>>>(W, Wt, 512, 1024);
    // 1. fused: Whh/T/WhT from Xh @ Wt (both halves + tanh + transpose)
    k_gemm1f<<<dim3(8, 64), 512, 0, stream>>>(Xh, Wt, Whh, T, WhT, aw, ab);
    // 2. S = T @ Whh^T  (fp16)  M=8192 N=8192 K=512, 256x128 tile, BK=64
    k_gemm2<<<dim3(64, 32), 512, 0, stream>>>(T, Whh, S);
    // 3. row softmax in place: S -> P (fp16)
    k_softmax_rows<<<dim3(8192), 256, 0, stream>>>(S, 8192);
    // 4. part[z] = P[:, z-chunk] @ Wh[z-chunk, :]  (BM=128 BN=256, BK=64, z=4)
    k_gemm3<<<dim3(2, 64, 4), 512, 0, stream>>>(S, WhT, part);
    // 5. outf = sum(part) + X, fused column stats (256 blocks)
    k_reduce_stats<<<dim3(256), 256, 0, stream>>>(part, X, outf, cs, cq);
    // 6. batchnorm + leaky relu
    k_bn_lrelu<<<dim3((8192 * 512) / 256), 256, 0, stream>>>(outf, cs, cq, out);
}